// Round 10
// baseline (169.766 us; speedup 1.0000x reference)
//
#include <hip/hip_runtime.h>

typedef __bf16 bf16_t;
typedef bf16_t bf16x8 __attribute__((ext_vector_type(8)));
typedef bf16_t bf16x4 __attribute__((ext_vector_type(4)));
typedef float f32x4 __attribute__((ext_vector_type(4)));
typedef unsigned int u32;

#define M_TOK 32768
#define NWIN 128
#define WIN  256

typedef __attribute__((address_space(3))) void* as3p;
typedef const __attribute__((address_space(1))) void* as1p;

__device__ __forceinline__ void gll16(const void* g, void* l) {
    __builtin_amdgcn_global_load_lds((as1p)g, (as3p)l, 16, 0, 0);
}

__device__ __forceinline__ bf16x8 cvt8(f32x4 a, f32x4 b) {
    bf16x8 o;
    o[0] = (bf16_t)a[0]; o[1] = (bf16_t)a[1]; o[2] = (bf16_t)a[2]; o[3] = (bf16_t)a[3];
    o[4] = (bf16_t)b[0]; o[5] = (bf16_t)b[1]; o[6] = (bf16_t)b[2]; o[7] = (bf16_t)b[3];
    return o;
}

#define VMW_(n) asm volatile("s_waitcnt vmcnt(" #n ")" ::: "memory")
#define VMW(n) VMW_(n)
#define LGKM0 asm volatile("s_waitcnt lgkmcnt(0)" ::: "memory")

#define MFMA16(b, a, c) __builtin_amdgcn_mfma_f32_16x16x32_bf16((b), (a), (c), 0, 0, 0)

// tiny fp32->bf16 weight convert (w_qkv 196608 + w_proj 65536 elems)
__global__ __launch_bounds__(256) void wconv(
    const float* __restrict__ wq, const float* __restrict__ wp,
    bf16_t* __restrict__ wqb, bf16_t* __restrict__ wpb)
{
    int i4 = (blockIdx.x * 256 + threadIdx.x) * 4;
    const float* s; bf16_t* dst; int idx;
    if (i4 < 196608) { s = wq; dst = wqb; idx = i4; }
    else             { s = wp; dst = wpb; idx = i4 - 196608; }
    f32x4 v = *(const f32x4*)(s + idx);
    bf16x4 o;
    o[0] = (bf16_t)v[0]; o[1] = (bf16_t)v[1]; o[2] = (bf16_t)v[2]; o[3] = (bf16_t)v[3];
    *(bf16x4*)(dst + idx) = o;
}

// Fused QKV-projection + windowed linear attention.
// v3 (r10): one block = (window, 2 heads); 512 blocks; LDS 66KB -> 2 blocks/CU.
//   X panel in regs (r9-verbatim loads); W K/V single-buffered 32KB (prefetch h+1
//   after KT/VT barrier); Q-weight b-frags from global L2 (r8-proven).
//   Ql/zin eliminated: phase-F Q a-frags assembled in-reg via shfl; z via in-reg
//   dot + shfl_xor reduce. 3 barriers/head. Phases A/B/C byte-level r8/r9-verified.
// MFMA convention (verified r5-r9): acc=mfma(b,a): a-frag lane(r,q)=A[m*16+r][q*8..],
// b-frag=B[n*16+r][q*8..], C: m-field=r (col), n-field=q*4+reg.
__global__ __launch_bounds__(512, 4) void fused_attn(
    const float* __restrict__ X,
    const bf16_t* __restrict__ Wq,    // [768][256] bf16: rows 0-255 Q, 256-511 K, 512-767 V
    const int* __restrict__ offsets,
    const int* __restrict__ counts,
    bf16_t* __restrict__ Y)           // [32768][256] bf16
{
    __shared__ __align__(16) bf16_t Wl[64 * 256];   // 32KB: K rows 0-31, V rows 32-63
    __shared__ __align__(16) bf16_t KT[32 * 256];   // 16KB (granule^c&7 swizzle)
    __shared__ __align__(16) bf16_t VT[32 * 256];   // 16KB
    __shared__ __align__(16) bf16_t kvb[32 * 32];   // 2KB  kv^T (rows d, cols c)
    __shared__ __align__(16) float sfp[32];

    // XCD-mapping: the 4 blocks of a window share bid&7 -> same XCD (X L2 reuse)
    const int bid = blockIdx.x;
    const int w  = (bid & 7) * 16 + ((bid >> 3) & 15);
    const int hp = bid >> 7;                 // head pair 0..3
    const int is64 = (counts[1] == 0) ? 1 : 0;
    const int off = offsets[w << is64];
    const int tid = threadIdx.x;
    const int lane = tid & 63;
    const int wv = tid >> 6;
    const int r = lane & 15, q = lane >> 4;

    // stage 64-row K/V panel for head h (pre-swizzled src granule, r7-r9 pattern)
    auto stageW = [&](int h) {
#pragma unroll
        for (int u = 0; u < 4; ++u) {
            const int rl = wv * 8 + u * 2 + (lane >> 5);     // 0..63, 2 rows/inst
            const int grow = (rl < 32 ? 256 + rl : 480 + rl) + h * 32;
            gll16(Wq + (size_t)grow * 256 + ((lane & 31) ^ (rl & 7)) * 8,
                  &Wl[(wv * 8 + u * 2) * 256]);
        }
    };

    // prologue: W(h0) DMA first, then X reg-loads (r9-verbatim)
    stageW(hp * 2);
    bf16x8 xr[2][8];   // X[t][kch*32+q*8..+7], t = wv*32 + i2*16 + r
#pragma unroll
    for (int i2 = 0; i2 < 2; ++i2) {
        const float* xp = X + (size_t)(off + wv * 32 + i2 * 16 + r) * 256 + q * 8;
#pragma unroll
        for (int kch = 0; kch < 8; ++kch) {
            f32x4 lo = *(const f32x4*)(xp + kch * 32);
            f32x4 hi = *(const f32x4*)(xp + kch * 32 + 4);
            xr[i2][kch] = cvt8(lo, hi);
        }
    }

    for (int h4 = 0; h4 < 2; ++h4) {
        const int h = hp * 2 + h4;
        VMW(0);                            // W(h) + prior Y stores drained
        __builtin_amdgcn_s_barrier();      // B1: Wl published
        __builtin_amdgcn_sched_barrier(0);

        // phase A: Q,K,V = X @ W^T (K/V b-frags LDS; Q b-frags global L2, r8-proven)
        f32x4 aQ[2][2] = {}, aK[2][2] = {}, aV[2][2] = {};
#pragma unroll
        for (int kch = 0; kch < 8; ++kch) {
            const int slot8 = (((kch * 4 + q) ^ (r & 7)) * 8);
#pragma unroll
            for (int ct = 0; ct < 2; ++ct) {
                bf16x8 bk = *(const bf16x8*)(Wl + (ct * 16 + r) * 256 + slot8);
                bf16x8 bv = *(const bf16x8*)(Wl + (32 + ct * 16 + r) * 256 + slot8);
                bf16x8 bq = *(const bf16x8*)(Wq + (size_t)(h * 32 + ct * 16 + r) * 256
                                              + kch * 32 + q * 8);
#pragma unroll
                for (int i2 = 0; i2 < 2; ++i2) {
                    aQ[i2][ct] = MFMA16(bq, xr[i2][kch], aQ[i2][ct]);
                    aK[i2][ct] = MFMA16(bk, xr[i2][kch], aK[i2][ct]);
                    aV[i2][ct] = MFMA16(bv, xr[i2][kch], aV[i2][ct]);
                }
            }
        }

        // phase B: transpose-store relu(K),V -> KT/VT (r8-verbatim)
#pragma unroll
        for (int i2 = 0; i2 < 2; ++i2) {
            const int t = wv * 32 + i2 * 16 + r;
            const int gt = t >> 3;
#pragma unroll
            for (int ct = 0; ct < 2; ++ct)
#pragma unroll
                for (int reg = 0; reg < 4; ++reg) {
                    const int c = ct * 16 + q * 4 + reg;
                    const int ei = c * 256 + (gt ^ (c & 7)) * 8 + (t & 7);
                    KT[ei] = (bf16_t)fmaxf(aK[i2][ct][reg], 0.f);
                    VT[ei] = (bf16_t)aV[i2][ct][reg];
                }
        }
        LGKM0;
        __builtin_amdgcn_s_barrier();      // B2: KT/VT published; all A-reads of Wl done
        __builtin_amdgcn_sched_barrier(0);
        if (h4 == 0) stageW(h + 1);        // overwrite Wl now; hides under C..F

        // phase C: kv-MFMA (waves 0-3) || s colsum (waves 4-7)  (r8-verbatim)
        if (wv < 4) {
            f32x4 kva = {};
            const int ct = wv >> 1, dt = wv & 1;
#pragma unroll
            for (int kch = 0; kch < 8; ++kch) {
                const int slot8 = (((kch * 4 + q) ^ (r & 7)) * 8);
                bf16x8 ak = *(const bf16x8*)(KT + (ct * 16 + r) * 256 + slot8);
                bf16x8 bv2 = *(const bf16x8*)(VT + (dt * 16 + r) * 256 + slot8);
                kva = MFMA16(bv2, ak, kva);     // kv[c=ct*16+r][d=dt*16+q*4+reg]
            }
#pragma unroll
            for (int reg = 0; reg < 4; ++reg)
                kvb[(dt * 16 + q * 4 + reg) * 32 + ct * 16 + r] = (bf16_t)kva[reg];
        } else {
            float sc = 0.f;
            const int tl = tid - 256;
            const int c = tl >> 3, p = tl & 7;
#pragma unroll
            for (int g = 0; g < 4; ++g) {       // all 32 granules, order-free sum
                bf16x8 kk = *(const bf16x8*)(KT + c * 256 + (p + g * 8) * 8);
#pragma unroll
                for (int j = 0; j < 8; ++j) sc += (float)kk[j];
            }
            sc += __shfl_xor(sc, 1);
            sc += __shfl_xor(sc, 2);
            sc += __shfl_xor(sc, 4);
            if ((tl & 7) == 0) sfp[tl >> 3] = sc;
        }
        LGKM0;
        __builtin_amdgcn_s_barrier();      // B3: kvb/sfp published
        __builtin_amdgcn_sched_barrier(0);

        // phase D': in-reg Q: relu+cvt, z via shfl-reduce, a-frag assembly via shfl
        bf16x8 qa[2];
        float zi[2];
#pragma unroll
        for (int i2 = 0; i2 < 2; ++i2) {
            bf16x4 o0, o1;
            float qb0[4], qb1[4];
#pragma unroll
            for (int reg = 0; reg < 4; ++reg) {
                o0[reg] = (bf16_t)fmaxf(aQ[i2][0][reg], 0.f);
                o1[reg] = (bf16_t)fmaxf(aQ[i2][1][reg], 0.f);
                qb0[reg] = (float)o0[reg];
                qb1[reg] = (float)o1[reg];
            }
            // z partial: lane holds channels {q*4..+3} u {16+q*4..+3} of token t
            f32x4 s0 = *(const f32x4*)&sfp[q * 4];
            f32x4 s1 = *(const f32x4*)&sfp[16 + q * 4];
            float zz = 0.f;
#pragma unroll
            for (int reg = 0; reg < 4; ++reg)
                zz += qb0[reg] * s0[reg] + qb1[reg] * s1[reg];
            zz += __shfl_xor(zz, 16);           // reduce over the 4 q-lanes of token
            zz += __shfl_xor(zz, 32);
            zi[i2] = 1.f / (zz + 1e-3f);
            // a-frag assembly: dest lane (r,q) wants u32 j = Q[t][q*8+2j, +1]
            // src lane r+16*(2(q&1)+(j>>1)), value pk[q>>1].{x:j even, y:j odd}
            u32 p0x, p0y, p1x, p1y;
            { uint2 t0 = *(uint2*)&o0; p0x = t0.x; p0y = t0.y; }
            { uint2 t1 = *(uint2*)&o1; p1x = t1.x; p1y = t1.y; }
            const int sl0 = r + 16 * (2 * (q & 1));
            const int sl1 = sl0 + 16;
            u32 a0 = __shfl((int)p0x, sl0), a1 = __shfl((int)p0y, sl0);
            u32 a2 = __shfl((int)p0x, sl1), a3 = __shfl((int)p0y, sl1);
            u32 b0 = __shfl((int)p1x, sl0), b1 = __shfl((int)p1y, sl0);
            u32 b2 = __shfl((int)p1x, sl1), b3 = __shfl((int)p1y, sl1);
            u32 wq4[4];
            const bool hi = (q >> 1) != 0;
            wq4[0] = hi ? b0 : a0; wq4[1] = hi ? b1 : a1;
            wq4[2] = hi ? b2 : a2; wq4[3] = hi ? b3 : a3;
            qa[i2] = *(bf16x8*)wq4;
        }

        // phase F: y = (Q.kv)*zinv -> Y (r8/r9-verbatim layout; zi lane-own token)
        {
            bf16x8 bk0 = *(const bf16x8*)(kvb + r * 32 + q * 8);
            bf16x8 bk1 = *(const bf16x8*)(kvb + (16 + r) * 32 + q * 8);
#pragma unroll
            for (int i2 = 0; i2 < 2; ++i2) {
                f32x4 y0 = {}, y1 = {};
                y0 = MFMA16(bk0, qa[i2], y0);
                y1 = MFMA16(bk1, qa[i2], y1);
                const int t = wv * 32 + i2 * 16 + r;
                bf16x4 o0, o1;
#pragma unroll
                for (int reg = 0; reg < 4; ++reg) {
                    o0[reg] = (bf16_t)(y0[reg] * zi[i2]);
                    o1[reg] = (bf16_t)(y1[reg] * zi[i2]);
                }
                bf16_t* yp = Y + (size_t)(off + t) * 256 + h * 32;
                *(bf16x4*)(yp + q * 4) = o0;
                *(bf16x4*)(yp + 16 + q * 4) = o1;
            }
        }
        // safety: F reads kvb/sfp; next writes to them are 2 barriers away (B1,B2)
    }
}

// GEMM2: Out = Y @ Wproj^T + b. 512 blocks x 512 thr, 64-row panel, 80KB LDS,
// 2 blocks/CU. Y panel (bf16) staged ONCE via gll16 pre-swizzled src;
// 2 n-blocks x 4 K-steps (BK=64).  [unchanged from r7-r9 — verified, ~6us]
__global__ __launch_bounds__(512) void gemm2_proj(
    const bf16_t* __restrict__ Y,
    const bf16_t* __restrict__ Wb,
    const float* __restrict__ bias,
    float* __restrict__ Out)
{
    __shared__ __align__(16) bf16_t Al[64][256];      // 32KB persistent A panel
    __shared__ __align__(16) bf16_t Bs[3][128][64];   // 48KB B triple buffer

    const int tid = threadIdx.x;
    const int lane = tid & 63;
    const int wv = tid >> 6;
    const int wm = wv >> 2, wn = wv & 3;
    const int m0 = blockIdx.x * 64;
    const int r = lane & 15, q = lane >> 4;
    const int rl = lane >> 3, gsl = lane & 7;

    f32x4 acc[2][2] = {};

    auto stageB = [&](int t) {
        const int nb = t >> 2, kc = (t & 3) * 64;
#pragma unroll
        for (int u = 0; u < 2; ++u)
            gll16(Wb + (size_t)(nb * 128 + wv * 16 + u * 8 + rl) * 256 + kc + (gsl ^ rl) * 8,
                  &Bs[t % 3][wv * 16 + u * 8][0]);
    };

    auto comp = [&](int t) {
        const int buf = t % 3;
#pragma unroll
        for (int s = 0; s < 2; ++s) {
            const int kk = (t & 3) * 2 + s;
            bf16x8 a[2], b[2];
#pragma unroll
            for (int i = 0; i < 2; ++i)
                a[i] = *(const bf16x8*)((const bf16_t*)Al +
                        (wm * 32 + i * 16 + r) * 256 + ((kk * 4 + q) ^ (r & 7)) * 8);
#pragma unroll
            for (int j = 0; j < 2; ++j)
                b[j] = *(const bf16x8*)&Bs[buf][wn * 32 + j * 16 + r][((s * 4 + q) ^ (r & 7)) * 8];
#pragma unroll
            for (int i = 0; i < 2; ++i)
#pragma unroll
                for (int j = 0; j < 2; ++j)
                    acc[i][j] = MFMA16(b[j], a[i], acc[i][j]);
        }
    };

    auto wout = [&](int nb) {
#pragma unroll
        for (int i = 0; i < 2; ++i) {
            const int rowg = m0 + wm * 32 + i * 16 + r;
#pragma unroll
            for (int j = 0; j < 2; ++j) {
                const int n = nb * 128 + wn * 32 + j * 16 + q * 4;
                f32x4 bi = *(const f32x4*)(bias + n);
                f32x4 o;
#pragma unroll
                for (int reg = 0; reg < 4; ++reg) o[reg] = acc[i][j][reg] + bi[reg];
                *(f32x4*)&Out[(size_t)rowg * 256 + n] = o;
                acc[i][j] = (f32x4){0.f, 0.f, 0.f, 0.f};
            }
        }
    };

    // A panel staged once: 4 gll16/wave (1 inst = 2 rows of 512B); src pre-swizzled
#pragma unroll
    for (int u = 0; u < 4; ++u) {
        const int rowl = wv * 8 + u * 2 + (lane >> 5);
        const int gsrc = (lane & 31) ^ (rowl & 7);
        gll16(Y + (size_t)(m0 + rowl) * 256 + gsrc * 8, &Al[wv * 8 + u * 2][0]);
    }
    stageB(0); stageB(1); stageB(2);   // total 10 insts in flight

#define G2S(t, NW) do { \
        VMW(NW); \
        __builtin_amdgcn_s_barrier(); \
        __builtin_amdgcn_sched_barrier(0); \
        comp(t); \
        if (((t) & 3) == 3) wout((t) >> 2); \
        __builtin_amdgcn_sched_barrier(0); \
        __builtin_amdgcn_s_barrier(); \
        if ((t) + 3 < 8) stageB((t) + 3); \
    } while (0)

    // t=0: VMW(4) retires A(4) + B0(2), leaves B1,B2
    G2S(0, 4); G2S(1, 4); G2S(2, 4); G2S(3, 4);
    G2S(4, 4); G2S(5, 4); G2S(6, 2); G2S(7, 0);
#undef G2S
}

extern "C" void kernel_launch(void* const* d_in, const int* in_sizes, int n_in,
                              void* d_out, int out_size, void* d_ws, size_t ws_size,
                              hipStream_t stream) {
    const float* x      = (const float*)d_in[0];
    const float* w_qkv  = (const float*)d_in[1];
    const float* w_proj = (const float*)d_in[2];
    const float* b_proj = (const float*)d_in[3];
    const int*   offs   = (const int*)d_in[4];
    const int*   cnts   = (const int*)d_in[5];

    char* ws = (char*)d_ws;
    bf16_t* Y   = (bf16_t*)(ws + 50331648);       // 16777216 B
    bf16_t* Wqb = (bf16_t*)(ws + 67108864);       //   393216 B
    bf16_t* Wpb = (bf16_t*)(ws + 67502080);       //   131072 B
    float*  out = (float*)d_out;

    // 0) weights fp32 -> bf16 (0.5 MB)
    wconv<<<256, 256, 0, stream>>>(w_qkv, w_proj, Wqb, Wpb);

    // 1) fused QKV-projection + windowed attention: (window, 2 heads)/block,
    //    66KB LDS -> 2 blocks/CU
    fused_attn<<<512, 512, 0, stream>>>(x, Wqb, offs, cnts, Y);

    // 2) proj gemm: 64-row panels, 2 blocks/CU, Y read once
    gemm2_proj<<<512, 512, 0, stream>>>(Y, Wpb, b_proj, out);
}

// Round 11
// 141.841 us; speedup vs baseline: 1.1969x; 1.1969x over previous
//
#include <hip/hip_runtime.h>

typedef __bf16 bf16_t;
typedef bf16_t bf16x8 __attribute__((ext_vector_type(8)));
typedef bf16_t bf16x4 __attribute__((ext_vector_type(4)));
typedef float f32x4 __attribute__((ext_vector_type(4)));
typedef unsigned int u32;

#define M_TOK 32768
#define NWIN 128
#define WIN  256

typedef __attribute__((address_space(3))) void* as3p;
typedef const __attribute__((address_space(1))) void* as1p;

__device__ __forceinline__ void gll16(const void* g, void* l) {
    __builtin_amdgcn_global_load_lds((as1p)g, (as3p)l, 16, 0, 0);
}

__device__ __forceinline__ bf16x8 cvt8(f32x4 a, f32x4 b) {
    bf16x8 o;
    o[0] = (bf16_t)a[0]; o[1] = (bf16_t)a[1]; o[2] = (bf16_t)a[2]; o[3] = (bf16_t)a[3];
    o[4] = (bf16_t)b[0]; o[5] = (bf16_t)b[1]; o[6] = (bf16_t)b[2]; o[7] = (bf16_t)b[3];
    return o;
}

#define VMW_(n) asm volatile("s_waitcnt vmcnt(" #n ")" ::: "memory")
#define VMW(n) VMW_(n)
#define LGKM0 asm volatile("s_waitcnt lgkmcnt(0)" ::: "memory")

#define MFMA16(b, a, c) __builtin_amdgcn_mfma_f32_16x16x32_bf16((b), (a), (c), 0, 0, 0)

// tiny fp32->bf16 weight convert (w_qkv 196608 + w_proj 65536 elems)
__global__ __launch_bounds__(256) void wconv(
    const float* __restrict__ wq, const float* __restrict__ wp,
    bf16_t* __restrict__ wqb, bf16_t* __restrict__ wpb)
{
    int i4 = (blockIdx.x * 256 + threadIdx.x) * 4;
    const float* s; bf16_t* dst; int idx;
    if (i4 < 196608) { s = wq; dst = wqb; idx = i4; }
    else             { s = wp; dst = wpb; idx = i4 - 196608; }
    f32x4 v = *(const f32x4*)(s + idx);
    bf16x4 o;
    o[0] = (bf16_t)v[0]; o[1] = (bf16_t)v[1]; o[2] = (bf16_t)v[2]; o[3] = (bf16_t)v[3];
    *(bf16x4*)(dst + idx) = o;
}

// Fused QKV-projection + windowed linear attention.
// v3.1 (r11): identical to r10's v3 EXCEPT plain __launch_bounds__(512) — the
// (512,4) min-waves clause capped VGPRs at 64 and spilled xr/acc to scratch
// (r10: FETCH 102MB, WRITE 155MB, 77us). Natural allocation (~124 VGPR <= 128)
// gives 4 waves/EU -> 2 blocks/CU by both VGPR and LDS (2x66KB <= 160KB).
// MFMA convention (verified r5-r10): acc=mfma(b,a): a-frag lane(r,q)=A[m*16+r][q*8..],
// b-frag=B[n*16+r][q*8..], C: m-field=r (col), n-field=q*4+reg.
__global__ __launch_bounds__(512) void fused_attn(
    const float* __restrict__ X,
    const bf16_t* __restrict__ Wq,    // [768][256] bf16: rows 0-255 Q, 256-511 K, 512-767 V
    const int* __restrict__ offsets,
    const int* __restrict__ counts,
    bf16_t* __restrict__ Y)           // [32768][256] bf16
{
    __shared__ __align__(16) bf16_t Wl[64 * 256];   // 32KB: K rows 0-31, V rows 32-63
    __shared__ __align__(16) bf16_t KT[32 * 256];   // 16KB (granule^c&7 swizzle)
    __shared__ __align__(16) bf16_t VT[32 * 256];   // 16KB
    __shared__ __align__(16) bf16_t kvb[32 * 32];   // 2KB  kv^T (rows d, cols c)
    __shared__ __align__(16) float sfp[32];

    // XCD-mapping: the 4 blocks of a window share bid&7 -> same XCD (X L2 reuse)
    const int bid = blockIdx.x;
    const int w  = (bid & 7) * 16 + ((bid >> 3) & 15);
    const int hp = bid >> 7;                 // head pair 0..3
    const int is64 = (counts[1] == 0) ? 1 : 0;
    const int off = offsets[w << is64];
    const int tid = threadIdx.x;
    const int lane = tid & 63;
    const int wv = tid >> 6;
    const int r = lane & 15, q = lane >> 4;

    // stage 64-row K/V panel for head h (pre-swizzled src granule, r7-r9 pattern)
    auto stageW = [&](int h) {
#pragma unroll
        for (int u = 0; u < 4; ++u) {
            const int rl = wv * 8 + u * 2 + (lane >> 5);     // 0..63, 2 rows/inst
            const int grow = (rl < 32 ? 256 + rl : 480 + rl) + h * 32;
            gll16(Wq + (size_t)grow * 256 + ((lane & 31) ^ (rl & 7)) * 8,
                  &Wl[(wv * 8 + u * 2) * 256]);
        }
    };

    // prologue: W(h0) DMA first, then X reg-loads (r9-verbatim)
    stageW(hp * 2);
    bf16x8 xr[2][8];   // X[t][kch*32+q*8..+7], t = wv*32 + i2*16 + r
#pragma unroll
    for (int i2 = 0; i2 < 2; ++i2) {
        const float* xp = X + (size_t)(off + wv * 32 + i2 * 16 + r) * 256 + q * 8;
#pragma unroll
        for (int kch = 0; kch < 8; ++kch) {
            f32x4 lo = *(const f32x4*)(xp + kch * 32);
            f32x4 hi = *(const f32x4*)(xp + kch * 32 + 4);
            xr[i2][kch] = cvt8(lo, hi);
        }
    }

    for (int h4 = 0; h4 < 2; ++h4) {
        const int h = hp * 2 + h4;
        VMW(0);                            // W(h) + prior Y stores drained
        __builtin_amdgcn_s_barrier();      // B1: Wl published
        __builtin_amdgcn_sched_barrier(0);

        // phase A: Q,K,V = X @ W^T (K/V b-frags LDS; Q b-frags global L2, r8-proven)
        f32x4 aQ[2][2] = {}, aK[2][2] = {}, aV[2][2] = {};
#pragma unroll
        for (int kch = 0; kch < 8; ++kch) {
            const int slot8 = (((kch * 4 + q) ^ (r & 7)) * 8);
#pragma unroll
            for (int ct = 0; ct < 2; ++ct) {
                bf16x8 bk = *(const bf16x8*)(Wl + (ct * 16 + r) * 256 + slot8);
                bf16x8 bv = *(const bf16x8*)(Wl + (32 + ct * 16 + r) * 256 + slot8);
                bf16x8 bq = *(const bf16x8*)(Wq + (size_t)(h * 32 + ct * 16 + r) * 256
                                              + kch * 32 + q * 8);
#pragma unroll
                for (int i2 = 0; i2 < 2; ++i2) {
                    aQ[i2][ct] = MFMA16(bq, xr[i2][kch], aQ[i2][ct]);
                    aK[i2][ct] = MFMA16(bk, xr[i2][kch], aK[i2][ct]);
                    aV[i2][ct] = MFMA16(bv, xr[i2][kch], aV[i2][ct]);
                }
            }
        }

        // phase B: transpose-store relu(K),V -> KT/VT (r8-verbatim)
#pragma unroll
        for (int i2 = 0; i2 < 2; ++i2) {
            const int t = wv * 32 + i2 * 16 + r;
            const int gt = t >> 3;
#pragma unroll
            for (int ct = 0; ct < 2; ++ct)
#pragma unroll
                for (int reg = 0; reg < 4; ++reg) {
                    const int c = ct * 16 + q * 4 + reg;
                    const int ei = c * 256 + (gt ^ (c & 7)) * 8 + (t & 7);
                    KT[ei] = (bf16_t)fmaxf(aK[i2][ct][reg], 0.f);
                    VT[ei] = (bf16_t)aV[i2][ct][reg];
                }
        }
        LGKM0;
        __builtin_amdgcn_s_barrier();      // B2: KT/VT published; all A-reads of Wl done
        __builtin_amdgcn_sched_barrier(0);
        if (h4 == 0) stageW(h + 1);        // overwrite Wl now; hides under C..F

        // phase C: kv-MFMA (waves 0-3) || s colsum (waves 4-7)  (r8-verbatim)
        if (wv < 4) {
            f32x4 kva = {};
            const int ct = wv >> 1, dt = wv & 1;
#pragma unroll
            for (int kch = 0; kch < 8; ++kch) {
                const int slot8 = (((kch * 4 + q) ^ (r & 7)) * 8);
                bf16x8 ak = *(const bf16x8*)(KT + (ct * 16 + r) * 256 + slot8);
                bf16x8 bv2 = *(const bf16x8*)(VT + (dt * 16 + r) * 256 + slot8);
                kva = MFMA16(bv2, ak, kva);     // kv[c=ct*16+r][d=dt*16+q*4+reg]
            }
#pragma unroll
            for (int reg = 0; reg < 4; ++reg)
                kvb[(dt * 16 + q * 4 + reg) * 32 + ct * 16 + r] = (bf16_t)kva[reg];
        } else {
            float sc = 0.f;
            const int tl = tid - 256;
            const int c = tl >> 3, p = tl & 7;
#pragma unroll
            for (int g = 0; g < 4; ++g) {       // all 32 granules, order-free sum
                bf16x8 kk = *(const bf16x8*)(KT + c * 256 + (p + g * 8) * 8);
#pragma unroll
                for (int j = 0; j < 8; ++j) sc += (float)kk[j];
            }
            sc += __shfl_xor(sc, 1);
            sc += __shfl_xor(sc, 2);
            sc += __shfl_xor(sc, 4);
            if ((tl & 7) == 0) sfp[tl >> 3] = sc;
        }
        LGKM0;
        __builtin_amdgcn_s_barrier();      // B3: kvb/sfp published
        __builtin_amdgcn_sched_barrier(0);

        // phase D': in-reg Q: relu+cvt, z via shfl-reduce, a-frag assembly via shfl
        bf16x8 qa[2];
        float zi[2];
#pragma unroll
        for (int i2 = 0; i2 < 2; ++i2) {
            bf16x4 o0, o1;
            float qb0[4], qb1[4];
#pragma unroll
            for (int reg = 0; reg < 4; ++reg) {
                o0[reg] = (bf16_t)fmaxf(aQ[i2][0][reg], 0.f);
                o1[reg] = (bf16_t)fmaxf(aQ[i2][1][reg], 0.f);
                qb0[reg] = (float)o0[reg];
                qb1[reg] = (float)o1[reg];
            }
            // z partial: lane holds channels {q*4..+3} u {16+q*4..+3} of token t
            f32x4 s0 = *(const f32x4*)&sfp[q * 4];
            f32x4 s1 = *(const f32x4*)&sfp[16 + q * 4];
            float zz = 0.f;
#pragma unroll
            for (int reg = 0; reg < 4; ++reg)
                zz += qb0[reg] * s0[reg] + qb1[reg] * s1[reg];
            zz += __shfl_xor(zz, 16);           // reduce over the 4 q-lanes of token
            zz += __shfl_xor(zz, 32);
            zi[i2] = 1.f / (zz + 1e-3f);
            // a-frag assembly: dest lane (r,q) wants u32 j = Q[t][q*8+2j, +1]
            // src lane r+16*(2(q&1)+(j>>1)), value pk[q>>1].{x:j even, y:j odd}
            u32 p0x, p0y, p1x, p1y;
            { uint2 t0 = *(uint2*)&o0; p0x = t0.x; p0y = t0.y; }
            { uint2 t1 = *(uint2*)&o1; p1x = t1.x; p1y = t1.y; }
            const int sl0 = r + 16 * (2 * (q & 1));
            const int sl1 = sl0 + 16;
            u32 a0 = __shfl((int)p0x, sl0), a1 = __shfl((int)p0y, sl0);
            u32 a2 = __shfl((int)p0x, sl1), a3 = __shfl((int)p0y, sl1);
            u32 b0 = __shfl((int)p1x, sl0), b1 = __shfl((int)p1y, sl0);
            u32 b2 = __shfl((int)p1x, sl1), b3 = __shfl((int)p1y, sl1);
            u32 wq4[4];
            const bool hi = (q >> 1) != 0;
            wq4[0] = hi ? b0 : a0; wq4[1] = hi ? b1 : a1;
            wq4[2] = hi ? b2 : a2; wq4[3] = hi ? b3 : a3;
            qa[i2] = *(bf16x8*)wq4;
        }

        // phase F: y = (Q.kv)*zinv -> Y (r8/r9-verbatim layout; zi lane-own token)
        {
            bf16x8 bk0 = *(const bf16x8*)(kvb + r * 32 + q * 8);
            bf16x8 bk1 = *(const bf16x8*)(kvb + (16 + r) * 32 + q * 8);
#pragma unroll
            for (int i2 = 0; i2 < 2; ++i2) {
                f32x4 y0 = {}, y1 = {};
                y0 = MFMA16(bk0, qa[i2], y0);
                y1 = MFMA16(bk1, qa[i2], y1);
                const int t = wv * 32 + i2 * 16 + r;
                bf16x4 o0, o1;
#pragma unroll
                for (int reg = 0; reg < 4; ++reg) {
                    o0[reg] = (bf16_t)(y0[reg] * zi[i2]);
                    o1[reg] = (bf16_t)(y1[reg] * zi[i2]);
                }
                bf16_t* yp = Y + (size_t)(off + t) * 256 + h * 32;
                *(bf16x4*)(yp + q * 4) = o0;
                *(bf16x4*)(yp + 16 + q * 4) = o1;
            }
        }
        // safety: F reads kvb/sfp; next writes to them are 2 barriers away (B1,B2)
    }
}

// GEMM2: Out = Y @ Wproj^T + b. 512 blocks x 512 thr, 64-row panel, 80KB LDS,
// 2 blocks/CU. Y panel (bf16) staged ONCE via gll16 pre-swizzled src;
// 2 n-blocks x 4 K-steps (BK=64).  [unchanged from r7-r9 — verified, ~6us]
__global__ __launch_bounds__(512) void gemm2_proj(
    const bf16_t* __restrict__ Y,
    const bf16_t* __restrict__ Wb,
    const float* __restrict__ bias,
    float* __restrict__ Out)
{
    __shared__ __align__(16) bf16_t Al[64][256];      // 32KB persistent A panel
    __shared__ __align__(16) bf16_t Bs[3][128][64];   // 48KB B triple buffer

    const int tid = threadIdx.x;
    const int lane = tid & 63;
    const int wv = tid >> 6;
    const int wm = wv >> 2, wn = wv & 3;
    const int m0 = blockIdx.x * 64;
    const int r = lane & 15, q = lane >> 4;
    const int rl = lane >> 3, gsl = lane & 7;

    f32x4 acc[2][2] = {};

    auto stageB = [&](int t) {
        const int nb = t >> 2, kc = (t & 3) * 64;
#pragma unroll
        for (int u = 0; u < 2; ++u)
            gll16(Wb + (size_t)(nb * 128 + wv * 16 + u * 8 + rl) * 256 + kc + (gsl ^ rl) * 8,
                  &Bs[t % 3][wv * 16 + u * 8][0]);
    };

    auto comp = [&](int t) {
        const int buf = t % 3;
#pragma unroll
        for (int s = 0; s < 2; ++s) {
            const int kk = (t & 3) * 2 + s;
            bf16x8 a[2], b[2];
#pragma unroll
            for (int i = 0; i < 2; ++i)
                a[i] = *(const bf16x8*)((const bf16_t*)Al +
                        (wm * 32 + i * 16 + r) * 256 + ((kk * 4 + q) ^ (r & 7)) * 8);
#pragma unroll
            for (int j = 0; j < 2; ++j)
                b[j] = *(const bf16x8*)&Bs[buf][wn * 32 + j * 16 + r][((s * 4 + q) ^ (r & 7)) * 8];
#pragma unroll
            for (int i = 0; i < 2; ++i)
#pragma unroll
                for (int j = 0; j < 2; ++j)
                    acc[i][j] = MFMA16(b[j], a[i], acc[i][j]);
        }
    };

    auto wout = [&](int nb) {
#pragma unroll
        for (int i = 0; i < 2; ++i) {
            const int rowg = m0 + wm * 32 + i * 16 + r;
#pragma unroll
            for (int j = 0; j < 2; ++j) {
                const int n = nb * 128 + wn * 32 + j * 16 + q * 4;
                f32x4 bi = *(const f32x4*)(bias + n);
                f32x4 o;
#pragma unroll
                for (int reg = 0; reg < 4; ++reg) o[reg] = acc[i][j][reg] + bi[reg];
                *(f32x4*)&Out[(size_t)rowg * 256 + n] = o;
                acc[i][j] = (f32x4){0.f, 0.f, 0.f, 0.f};
            }
        }
    };

    // A panel staged once: 4 gll16/wave (1 inst = 2 rows of 512B); src pre-swizzled
#pragma unroll
    for (int u = 0; u < 4; ++u) {
        const int rowl = wv * 8 + u * 2 + (lane >> 5);
        const int gsrc = (lane & 31) ^ (rowl & 7);
        gll16(Y + (size_t)(m0 + rowl) * 256 + gsrc * 8, &Al[wv * 8 + u * 2][0]);
    }
    stageB(0); stageB(1); stageB(2);   // total 10 insts in flight

#define G2S(t, NW) do { \
        VMW(NW); \
        __builtin_amdgcn_s_barrier(); \
        __builtin_amdgcn_sched_barrier(0); \
        comp(t); \
        if (((t) & 3) == 3) wout((t) >> 2); \
        __builtin_amdgcn_sched_barrier(0); \
        __builtin_amdgcn_s_barrier(); \
        if ((t) + 3 < 8) stageB((t) + 3); \
    } while (0)

    // t=0: VMW(4) retires A(4) + B0(2), leaves B1,B2
    G2S(0, 4); G2S(1, 4); G2S(2, 4); G2S(3, 4);
    G2S(4, 4); G2S(5, 4); G2S(6, 2); G2S(7, 0);
#undef G2S
}

extern "C" void kernel_launch(void* const* d_in, const int* in_sizes, int n_in,
                              void* d_out, int out_size, void* d_ws, size_t ws_size,
                              hipStream_t stream) {
    const float* x      = (const float*)d_in[0];
    const float* w_qkv  = (const float*)d_in[1];
    const float* w_proj = (const float*)d_in[2];
    const float* b_proj = (const float*)d_in[3];
    const int*   offs   = (const int*)d_in[4];
    const int*   cnts   = (const int*)d_in[5];

    char* ws = (char*)d_ws;
    bf16_t* Y   = (bf16_t*)(ws + 50331648);       // 16777216 B
    bf16_t* Wqb = (bf16_t*)(ws + 67108864);       //   393216 B
    bf16_t* Wpb = (bf16_t*)(ws + 67502080);       //   131072 B
    float*  out = (float*)d_out;

    // 0) weights fp32 -> bf16 (0.5 MB)
    wconv<<<256, 256, 0, stream>>>(w_qkv, w_proj, Wqb, Wpb);

    // 1) fused QKV-projection + windowed attention: (window, 2 heads)/block,
    //    66KB LDS, natural VGPR allocation -> 2 blocks/CU
    fused_attn<<<512, 512, 0, stream>>>(x, Wqb, offs, cnts, Y);

    // 2) proj gemm: 64-row panels, 2 blocks/CU, Y read once
    gemm2_proj<<<512, 512, 0, stream>>>(Y, Wpb, b_proj, out);
}

// Round 12
// 130.912 us; speedup vs baseline: 1.2968x; 1.0835x over previous
//
#include <hip/hip_runtime.h>

typedef __bf16 bf16_t;
typedef bf16_t bf16x8 __attribute__((ext_vector_type(8)));
typedef bf16_t bf16x4 __attribute__((ext_vector_type(4)));
typedef float f32x4 __attribute__((ext_vector_type(4)));
typedef unsigned int u32;

#define M_TOK 32768
#define NWIN 128
#define WIN  256

typedef __attribute__((address_space(3))) void* as3p;
typedef const __attribute__((address_space(1))) void* as1p;

__device__ __forceinline__ void gll16(const void* g, void* l) {
    __builtin_amdgcn_global_load_lds((as1p)g, (as3p)l, 16, 0, 0);
}

__device__ __forceinline__ bf16x8 cvt8(f32x4 a, f32x4 b) {
    bf16x8 o;
    o[0] = (bf16_t)a[0]; o[1] = (bf16_t)a[1]; o[2] = (bf16_t)a[2]; o[3] = (bf16_t)a[3];
    o[4] = (bf16_t)b[0]; o[5] = (bf16_t)b[1]; o[6] = (bf16_t)b[2]; o[7] = (bf16_t)b[3];
    return o;
}

#define VMW_(n) asm volatile("s_waitcnt vmcnt(" #n ")" ::: "memory")
#define VMW(n) VMW_(n)
#define LGKM0 asm volatile("s_waitcnt lgkmcnt(0)" ::: "memory")

#define MFMA16(b, a, c) __builtin_amdgcn_mfma_f32_16x16x32_bf16((b), (a), (c), 0, 0, 0)

// tiny fp32->bf16 weight convert (w_qkv 196608 + w_proj 65536 elems)
__global__ __launch_bounds__(256) void wconv(
    const float* __restrict__ wq, const float* __restrict__ wp,
    bf16_t* __restrict__ wqb, bf16_t* __restrict__ wpb)
{
    int i4 = (blockIdx.x * 256 + threadIdx.x) * 4;
    const float* s; bf16_t* dst; int idx;
    if (i4 < 196608) { s = wq; dst = wqb; idx = i4; }
    else             { s = wp; dst = wpb; idx = i4 - 196608; }
    f32x4 v = *(const f32x4*)(s + idx);
    bf16x4 o;
    o[0] = (bf16_t)v[0]; o[1] = (bf16_t)v[1]; o[2] = (bf16_t)v[2]; o[3] = (bf16_t)v[3];
    *(bf16x4*)(dst + idx) = o;
}

// Fused QKV-projection + windowed linear attention.
// v4 (r12): r9's 4-heads/block + W 96-row double-buffer (prologue amortized 4x)
//   combined with r11's verified D'-shuffle path (no Ql/zin LDS, no phase E)
//   and counted head-top waits VMW(16) (W prefetch retired, Y-store acks left
//   in flight). 3 barriers/head. All phase bodies verbatim from r9/r11 passes.
// MFMA convention (verified r5-r11): acc=mfma(b,a): a-frag lane(r,q)=A[m*16+r][q*8..],
// b-frag=B[n*16+r][q*8..], C: m-field=r (col), n-field=q*4+reg.
__global__ __launch_bounds__(512) void fused_attn(
    const float* __restrict__ X,
    const bf16_t* __restrict__ Wq,    // [768][256] bf16: rows 0-255 Q, 256-511 K, 512-767 V
    const int* __restrict__ offsets,
    const int* __restrict__ counts,
    bf16_t* __restrict__ Y)           // [32768][256] bf16
{
    __shared__ __align__(16) bf16_t Wl2[2][96 * 256];   // 96KB dbuf W panel (K|V|Q)
    __shared__ __align__(16) bf16_t KT[32 * 256];       // 16KB (granule^c&7 swizzle)
    __shared__ __align__(16) bf16_t VT[32 * 256];       // 16KB
    __shared__ __align__(16) bf16_t kvb[32 * 32];       // 2KB kv^T (rows d, cols c)
    __shared__ __align__(16) float sfp[32];

    // XCD-pairing: window's two head-halves -> same XCD (bids congruent mod 8)
    const int bid = blockIdx.x;
    const int w  = (bid & 7) * 16 + (bid >> 4);
    const int hh = (bid >> 3) & 1;
    const int is64 = (counts[1] == 0) ? 1 : 0;
    const int off = offsets[w << is64];
    const int tid = threadIdx.x;
    const int lane = tid & 63;
    const int wv = tid >> 6;
    const int r = lane & 15, q = lane >> 4;

    // stage 96-row W panel for head h: rows 0-31 K, 32-63 V, 64-95 Q (r9-verbatim)
    auto stageW = [&](int h, int buf) {
#pragma unroll
        for (int u = 0; u < 6; ++u) {
            const int rl = wv * 12 + u * 2 + (lane >> 5);   // 0..95, 2 rows/inst
            const int grow = (rl < 32 ? 256 + rl : (rl < 64 ? 480 + rl : rl - 64)) + h * 32;
            gll16(Wq + (size_t)grow * 256 + ((lane & 31) ^ (rl & 7)) * 8,
                  &Wl2[buf][(wv * 12 + u * 2) * 256]);
        }
    };

    // prologue: W(h0) DMA first, then X reg-loads (r9-verbatim; cvt waits retire W too)
    stageW(hh * 4, 0);
    bf16x8 xr[2][8];   // X[t][kch*32+q*8..+7], t = wv*32 + i2*16 + r
#pragma unroll
    for (int i2 = 0; i2 < 2; ++i2) {
        const float* xp = X + (size_t)(off + wv * 32 + i2 * 16 + r) * 256 + q * 8;
#pragma unroll
        for (int kch = 0; kch < 8; ++kch) {
            f32x4 lo = *(const f32x4*)(xp + kch * 32);
            f32x4 hi = *(const f32x4*)(xp + kch * 32 + 4);
            xr[i2][kch] = cvt8(lo, hi);
        }
    }

#pragma unroll
    for (int h4 = 0; h4 < 4; ++h4) {
        const int h = hh * 4 + h4;
        const int buf = h4 & 1;
        // counted wait: queue at top = [W(h) x6, stores(h-1) x16] -> <=16 retires W
        if (h4 == 0) { VMW(0); } else { VMW(16); }
        __builtin_amdgcn_s_barrier();      // B1: Wl[buf] published
        __builtin_amdgcn_sched_barrier(0);
        const bf16_t* Wl = &Wl2[buf][0];

        // phase A: Q,K,V = X @ W^T, all b-frags from LDS panel (r9-verbatim)
        f32x4 aQ[2][2] = {}, aK[2][2] = {}, aV[2][2] = {};
#pragma unroll
        for (int kch = 0; kch < 8; ++kch) {
            const int slot8 = (((kch * 4 + q) ^ (r & 7)) * 8);
#pragma unroll
            for (int ct = 0; ct < 2; ++ct) {
                bf16x8 bk = *(const bf16x8*)(Wl + (ct * 16 + r) * 256 + slot8);
                bf16x8 bv = *(const bf16x8*)(Wl + (32 + ct * 16 + r) * 256 + slot8);
                bf16x8 bq = *(const bf16x8*)(Wl + (64 + ct * 16 + r) * 256 + slot8);
#pragma unroll
                for (int i2 = 0; i2 < 2; ++i2) {
                    aQ[i2][ct] = MFMA16(bq, xr[i2][kch], aQ[i2][ct]);
                    aK[i2][ct] = MFMA16(bk, xr[i2][kch], aK[i2][ct]);
                    aV[i2][ct] = MFMA16(bv, xr[i2][kch], aV[i2][ct]);
                }
            }
        }
        // prefetch next head's W panel; hides under phases B..F
        if (h4 < 3) stageW(h + 1, buf ^ 1);

        // phase B: transpose-store relu(K),V -> KT/VT (r8/r9-verbatim)
#pragma unroll
        for (int i2 = 0; i2 < 2; ++i2) {
            const int t = wv * 32 + i2 * 16 + r;
            const int gt = t >> 3;
#pragma unroll
            for (int ct = 0; ct < 2; ++ct)
#pragma unroll
                for (int reg = 0; reg < 4; ++reg) {
                    const int c = ct * 16 + q * 4 + reg;
                    const int ei = c * 256 + (gt ^ (c & 7)) * 8 + (t & 7);
                    KT[ei] = (bf16_t)fmaxf(aK[i2][ct][reg], 0.f);
                    VT[ei] = (bf16_t)aV[i2][ct][reg];
                }
        }
        LGKM0;                             // publish ds_writes, keep gll16 in flight
        __builtin_amdgcn_s_barrier();      // B2: KT/VT published
        __builtin_amdgcn_sched_barrier(0);

        // phase C: kv-MFMA (waves 0-3, writes kvb) || s colsum (waves 4-7) (r11-verbatim)
        if (wv < 4) {
            f32x4 kva = {};
            const int ct = wv >> 1, dt = wv & 1;
#pragma unroll
            for (int kch = 0; kch < 8; ++kch) {
                const int slot8 = (((kch * 4 + q) ^ (r & 7)) * 8);
                bf16x8 ak = *(const bf16x8*)(KT + (ct * 16 + r) * 256 + slot8);
                bf16x8 bv2 = *(const bf16x8*)(VT + (dt * 16 + r) * 256 + slot8);
                kva = MFMA16(bv2, ak, kva);     // kv[c=ct*16+r][d=dt*16+q*4+reg]
            }
#pragma unroll
            for (int reg = 0; reg < 4; ++reg)
                kvb[(dt * 16 + q * 4 + reg) * 32 + ct * 16 + r] = (bf16_t)kva[reg];
        } else {
            float sc = 0.f;
            const int tl = tid - 256;
            const int c = tl >> 3, p = tl & 7;
#pragma unroll
            for (int g = 0; g < 4; ++g) {       // all 32 granules, order-free sum
                bf16x8 kk = *(const bf16x8*)(KT + c * 256 + (p + g * 8) * 8);
#pragma unroll
                for (int j = 0; j < 8; ++j) sc += (float)kk[j];
            }
            sc += __shfl_xor(sc, 1);
            sc += __shfl_xor(sc, 2);
            sc += __shfl_xor(sc, 4);
            if ((tl & 7) == 0) sfp[tl >> 3] = sc;
        }
        LGKM0;
        __builtin_amdgcn_s_barrier();      // B3: kvb/sfp published
        __builtin_amdgcn_sched_barrier(0);

        // phase D': in-reg Q relu+cvt, z via shfl-reduce, a-frag via shfl (r11-verbatim)
        bf16x8 qa[2];
        float zi[2];
#pragma unroll
        for (int i2 = 0; i2 < 2; ++i2) {
            bf16x4 o0, o1;
            float qb0[4], qb1[4];
#pragma unroll
            for (int reg = 0; reg < 4; ++reg) {
                o0[reg] = (bf16_t)fmaxf(aQ[i2][0][reg], 0.f);
                o1[reg] = (bf16_t)fmaxf(aQ[i2][1][reg], 0.f);
                qb0[reg] = (float)o0[reg];
                qb1[reg] = (float)o1[reg];
            }
            f32x4 s0 = *(const f32x4*)&sfp[q * 4];
            f32x4 s1 = *(const f32x4*)&sfp[16 + q * 4];
            float zz = 0.f;
#pragma unroll
            for (int reg = 0; reg < 4; ++reg)
                zz += qb0[reg] * s0[reg] + qb1[reg] * s1[reg];
            zz += __shfl_xor(zz, 16);           // reduce over the 4 q-lanes of token
            zz += __shfl_xor(zz, 32);
            zi[i2] = 1.f / (zz + 1e-3f);
            u32 p0x, p0y, p1x, p1y;
            { uint2 t0 = *(uint2*)&o0; p0x = t0.x; p0y = t0.y; }
            { uint2 t1 = *(uint2*)&o1; p1x = t1.x; p1y = t1.y; }
            const int sl0 = r + 16 * (2 * (q & 1));
            const int sl1 = sl0 + 16;
            u32 a0 = __shfl((int)p0x, sl0), a1 = __shfl((int)p0y, sl0);
            u32 a2 = __shfl((int)p0x, sl1), a3 = __shfl((int)p0y, sl1);
            u32 b0 = __shfl((int)p1x, sl0), b1 = __shfl((int)p1y, sl0);
            u32 b2 = __shfl((int)p1x, sl1), b3 = __shfl((int)p1y, sl1);
            u32 wq4[4];
            const bool hi = (q >> 1) != 0;
            wq4[0] = hi ? b0 : a0; wq4[1] = hi ? b1 : a1;
            wq4[2] = hi ? b2 : a2; wq4[3] = hi ? b3 : a3;
            qa[i2] = *(bf16x8*)wq4;
        }

        // phase F: y = (Q.kv)*zinv -> Y (r11-verbatim)
        {
            bf16x8 bk0 = *(const bf16x8*)(kvb + r * 32 + q * 8);
            bf16x8 bk1 = *(const bf16x8*)(kvb + (16 + r) * 32 + q * 8);
#pragma unroll
            for (int i2 = 0; i2 < 2; ++i2) {
                f32x4 y0 = {}, y1 = {};
                y0 = MFMA16(bk0, qa[i2], y0);
                y1 = MFMA16(bk1, qa[i2], y1);
                const int t = wv * 32 + i2 * 16 + r;
                bf16x4 o0, o1;
#pragma unroll
                for (int reg = 0; reg < 4; ++reg) {
                    o0[reg] = (bf16_t)(y0[reg] * zi[i2]);
                    o1[reg] = (bf16_t)(y1[reg] * zi[i2]);
                }
                bf16_t* yp = Y + (size_t)(off + t) * 256 + h * 32;
                *(bf16x4*)(yp + q * 4) = o0;
                *(bf16x4*)(yp + 16 + q * 4) = o1;
            }
        }
        // F reads kvb/sfp; next writes to them (C of h+1) are 2 barriers away (B1,B2)
    }
}

// GEMM2: Out = Y @ Wproj^T + b. 512 blocks x 512 thr, 64-row panel, 80KB LDS,
// 2 blocks/CU. Y panel (bf16) staged ONCE via gll16 pre-swizzled src;
// 2 n-blocks x 4 K-steps (BK=64).  [unchanged from r7-r11 — verified, ~6us]
__global__ __launch_bounds__(512) void gemm2_proj(
    const bf16_t* __restrict__ Y,
    const bf16_t* __restrict__ Wb,
    const float* __restrict__ bias,
    float* __restrict__ Out)
{
    __shared__ __align__(16) bf16_t Al[64][256];      // 32KB persistent A panel
    __shared__ __align__(16) bf16_t Bs[3][128][64];   // 48KB B triple buffer

    const int tid = threadIdx.x;
    const int lane = tid & 63;
    const int wv = tid >> 6;
    const int wm = wv >> 2, wn = wv & 3;
    const int m0 = blockIdx.x * 64;
    const int r = lane & 15, q = lane >> 4;
    const int rl = lane >> 3, gsl = lane & 7;

    f32x4 acc[2][2] = {};

    auto stageB = [&](int t) {
        const int nb = t >> 2, kc = (t & 3) * 64;
#pragma unroll
        for (int u = 0; u < 2; ++u)
            gll16(Wb + (size_t)(nb * 128 + wv * 16 + u * 8 + rl) * 256 + kc + (gsl ^ rl) * 8,
                  &Bs[t % 3][wv * 16 + u * 8][0]);
    };

    auto comp = [&](int t) {
        const int buf = t % 3;
#pragma unroll
        for (int s = 0; s < 2; ++s) {
            const int kk = (t & 3) * 2 + s;
            bf16x8 a[2], b[2];
#pragma unroll
            for (int i = 0; i < 2; ++i)
                a[i] = *(const bf16x8*)((const bf16_t*)Al +
                        (wm * 32 + i * 16 + r) * 256 + ((kk * 4 + q) ^ (r & 7)) * 8);
#pragma unroll
            for (int j = 0; j < 2; ++j)
                b[j] = *(const bf16x8*)&Bs[buf][wn * 32 + j * 16 + r][((s * 4 + q) ^ (r & 7)) * 8];
#pragma unroll
            for (int i = 0; i < 2; ++i)
#pragma unroll
                for (int j = 0; j < 2; ++j)
                    acc[i][j] = MFMA16(b[j], a[i], acc[i][j]);
        }
    };

    auto wout = [&](int nb) {
#pragma unroll
        for (int i = 0; i < 2; ++i) {
            const int rowg = m0 + wm * 32 + i * 16 + r;
#pragma unroll
            for (int j = 0; j < 2; ++j) {
                const int n = nb * 128 + wn * 32 + j * 16 + q * 4;
                f32x4 bi = *(const f32x4*)(bias + n);
                f32x4 o;
#pragma unroll
                for (int reg = 0; reg < 4; ++reg) o[reg] = acc[i][j][reg] + bi[reg];
                *(f32x4*)&Out[(size_t)rowg * 256 + n] = o;
                acc[i][j] = (f32x4){0.f, 0.f, 0.f, 0.f};
            }
        }
    };

    // A panel staged once: 4 gll16/wave (1 inst = 2 rows of 512B); src pre-swizzled
#pragma unroll
    for (int u = 0; u < 4; ++u) {
        const int rowl = wv * 8 + u * 2 + (lane >> 5);
        const int gsrc = (lane & 31) ^ (rowl & 7);
        gll16(Y + (size_t)(m0 + rowl) * 256 + gsrc * 8, &Al[wv * 8 + u * 2][0]);
    }
    stageB(0); stageB(1); stageB(2);   // total 10 insts in flight

#define G2S(t, NW) do { \
        VMW(NW); \
        __builtin_amdgcn_s_barrier(); \
        __builtin_amdgcn_sched_barrier(0); \
        comp(t); \
        if (((t) & 3) == 3) wout((t) >> 2); \
        __builtin_amdgcn_sched_barrier(0); \
        __builtin_amdgcn_s_barrier(); \
        if ((t) + 3 < 8) stageB((t) + 3); \
    } while (0)

    // t=0: VMW(4) retires A(4) + B0(2), leaves B1,B2
    G2S(0, 4); G2S(1, 4); G2S(2, 4); G2S(3, 4);
    G2S(4, 4); G2S(5, 4); G2S(6, 2); G2S(7, 0);
#undef G2S
}

extern "C" void kernel_launch(void* const* d_in, const int* in_sizes, int n_in,
                              void* d_out, int out_size, void* d_ws, size_t ws_size,
                              hipStream_t stream) {
    const float* x      = (const float*)d_in[0];
    const float* w_qkv  = (const float*)d_in[1];
    const float* w_proj = (const float*)d_in[2];
    const float* b_proj = (const float*)d_in[3];
    const int*   offs   = (const int*)d_in[4];
    const int*   cnts   = (const int*)d_in[5];

    char* ws = (char*)d_ws;
    bf16_t* Y   = (bf16_t*)(ws + 50331648);       // 16777216 B
    bf16_t* Wqb = (bf16_t*)(ws + 67108864);       //   393216 B
    bf16_t* Wpb = (bf16_t*)(ws + 67502080);       //   131072 B
    float*  out = (float*)d_out;

    // 0) weights fp32 -> bf16 (0.5 MB)
    wconv<<<256, 256, 0, stream>>>(w_qkv, w_proj, Wqb, Wpb);

    // 1) fused QKV-projection + windowed attention: (window, 4 heads)/block,
    //    W dbuf, D'-shuffle epilogue, counted head-top waits
    fused_attn<<<256, 512, 0, stream>>>(x, Wqb, offs, cnts, Y);

    // 2) proj gemm: 64-row panels, 2 blocks/CU, Y read once
    gemm2_proj<<<512, 512, 0, stream>>>(Y, Wpb, b_proj, out);
}